// Round 6
// baseline (30972.235 us; speedup 1.0000x reference)
//
#include <hip/hip_runtime.h>
#include <cstdint>
#include <cstddef>

// ---------------------------------------------------------------------------
// 2-layer LSTM (B=256, S=1024, V=H=256) + FC + log_softmax, MI355X/gfx950.
//
// Round 6: intra-WG recurrence. The LSTM recurrence never mixes batch rows,
// so 1 WG = 16 batch rows x all 256 units x 4 gates has NO cross-WG dep
// within a layer: per-step sync = __syncthreads + 8KB LDS double buffer.
// 32 WGs x 1024 thr (16 waves): WG m<16 = layer0 m-group, m+16 = layer1.
// L0->L1 handoff: L0 re-publishes its LDS-read A-fragments (= h1[t] in
// fragment layout) as coalesced 16B stores; L1 prefetches them coalesced
// one step ahead (sentinel + rare agent-atomic repair). x pre-packed to
// bf16 fragment layout once (pack_x).
//
// Phases: pack_w x5 -> pack_x -> memset h1p sentinels -> lstm_dual -> fc_lsm.
// Workspace ~405 MB: packed weights | xp (134MB) | h1p (134MB) | h2 (134MB)
// ---------------------------------------------------------------------------

typedef __attribute__((ext_vector_type(8))) short bf16x8;
typedef __attribute__((ext_vector_type(4))) float f32x4;

#define DEVFN __device__ __forceinline__

constexpr unsigned SENT = 0xFFFFFFFFu;   // bf16 NaN pair: unreachable for tanh outputs

DEVFN unsigned short f2bf(float f) {
  union { float f; unsigned u; } v; v.f = f;
  unsigned r = v.u + 0x7FFFu + ((v.u >> 16) & 1u);   // RNE
  return (unsigned short)(r >> 16);
}
// XOR swizzle inside a [rows][512B] LDS tile: 16B slot ^= (row&7)
DEVFN int swz(int row, int colbyte) {
  return row * 512 + ((((colbyte >> 4) ^ (row & 7)) << 4) | (colbyte & 15));
}
DEVFN float sigm(float x) { return __builtin_amdgcn_rcpf(1.f + __expf(-x)); }
DEVFN float tanhfast(float x) {
  float ax = fabsf(x);
  float e  = __expf(-2.f * ax);
  float t  = (1.f - e) * __builtin_amdgcn_rcpf(1.f + e);
  return copysignf(t, x);
}
DEVFN unsigned aload(const unsigned* p) {
  return __hip_atomic_load(p, __ATOMIC_RELAXED, __HIP_MEMORY_SCOPE_AGENT);
}
DEVFN bf16x8 frag_of(unsigned d0, unsigned d1, unsigned d2, unsigned d3) {
  union { uint4 u; bf16x8 v; } t;
  t.u = make_uint4(d0, d1, d2, d3);
  return t.v;
}
DEVFN bf16x8 frag4(uint4 u) {
  union { uint4 u; bf16x8 v; } t; t.u = u; return t.v;
}

// --------------------------------------------------------------------------
// Pack W[col][k] (K=256) into B-fragment tiles:
//   dst[((nt*8+kt)*64+lane)*8 + j] = bf16( W[nt*16+(lane&15)][kt*32+(lane>>4)*8+j] )
// --------------------------------------------------------------------------
__global__ void pack_w(const float* __restrict__ w, unsigned short* __restrict__ dst) {
  int bid = blockIdx.x;           // nt*8 + kt
  int lane = threadIdx.x;
  int col = (bid >> 3) * 16 + (lane & 15);
  int k0  = (bid & 7) * 32 + (lane >> 4) * 8;
  const float* src = w + (size_t)col * 256 + k0;
  unsigned short* d = dst + ((size_t)bid * 64 + lane) * 8;
#pragma unroll
  for (int j = 0; j < 8; ++j) d[j] = f2bf(src[j]);
}

// --------------------------------------------------------------------------
// pack_x: x[b][t][v] f32 -> xp fragment layout bf16:
//   xp16B[((t*16+m)*8+kt)*64 + lane] = bf16( x[16m+(lane&15)][t][kt*32+(lane>>4)*8 + 0..7] )
// grid = 1024 blocks x 64 thr: bid = ((m*8+kt)*8 + tc), t in [tc*128, tc*128+128)
// --------------------------------------------------------------------------
__global__ void pack_x(const float* __restrict__ x, unsigned short* __restrict__ xp) {
  int bid = blockIdx.x, lane = threadIdx.x;
  int tc = bid & 7, kt = (bid >> 3) & 7, m = bid >> 6;
  int row = lane & 15, hi = lane >> 4;
  for (int t = tc * 128; t < tc * 128 + 128; ++t) {
    const float* s = x + ((size_t)(16 * m + row) * 1024 + t) * 256 + kt * 32 + hi * 8;
    float4 f0 = *(const float4*)s;
    float4 f1 = *(const float4*)(s + 4);
    uint4 o;
    o.x = f2bf(f0.x) | ((unsigned)f2bf(f0.y) << 16);
    o.y = f2bf(f0.z) | ((unsigned)f2bf(f0.w) << 16);
    o.z = f2bf(f1.x) | ((unsigned)f2bf(f1.y) << 16);
    o.w = f2bf(f1.z) | ((unsigned)f2bf(f1.w) << 16);
    *(uint4*)(xp + ((((size_t)t * 16 + m) * 8 + kt) * 64 + lane) * 8) = o;
  }
}

// --------------------------------------------------------------------------
// Dual-layer LSTM, intra-WG recurrence. grid = 32 WGs x 1024 thr (16 waves).
// bid<16: layer0 m-group bid; bid>=16: layer1 m-group bid-16 (same XCD pair
// under bid%8). Wave wv owns units [16wv,16wv+16) x 4 gates; weights
// register-resident (256 VGPR). Per step: one barrier, LDS h double-buffer.
// --------------------------------------------------------------------------
__global__ __launch_bounds__(1024, 1) void lstm_dual(
    const unsigned short* __restrict__ xp,
    const unsigned short* __restrict__ Wih0, const unsigned short* __restrict__ Whh0,
    const float* __restrict__ bih0, const float* __restrict__ bhh0,
    const unsigned short* __restrict__ Wih1, const unsigned short* __restrict__ Whh1,
    const float* __restrict__ bih1, const float* __restrict__ bhh1,
    unsigned short* __restrict__ h1p, unsigned short* __restrict__ h2)
{
  __shared__ char ha[2][8192];          // h[16 rows][512B] bf16, swizzled
  const int tid = threadIdx.x;
  const int wv = tid >> 6, lane = tid & 63;
  const bool isL1 = blockIdx.x >= 16;
  const int m = (int)blockIdx.x & 15;
  const int u  = wv * 16 + (lane & 15);
  const int r0 = (lane >> 4) * 4;       // first of this lane's 4 C rows
  const int row = lane & 15, hi = lane >> 4;

  const unsigned short* Wih = isL1 ? Wih1 : Wih0;
  const unsigned short* Whh = isL1 ? Whh1 : Whh0;
  const float* bihp = isL1 ? bih1 : bih0;
  const float* bhhp = isL1 ? bhh1 : bhh0;

  // register-resident weight B-fragments: nt = g*16 + wv
  bf16x8 bwih[4][8], bwhh[4][8];
#pragma unroll
  for (int g = 0; g < 4; ++g)
#pragma unroll
    for (int kt = 0; kt < 8; ++kt) {
      bwih[g][kt] = *(const bf16x8*)(Wih +
          ((((size_t)(g * 16 + wv)) * 8 + kt) * 64 + lane) * 8);
      bwhh[g][kt] = *(const bf16x8*)(Whh +
          ((((size_t)(g * 16 + wv)) * 8 + kt) * 64 + lane) * 8);
    }

  float bias[4];
#pragma unroll
  for (int g = 0; g < 4; ++g) bias[g] = bihp[g * 256 + u] + bhhp[g * 256 + u];

  float c[4] = {0.f, 0.f, 0.f, 0.f};

  if (!isL1) {
    // ================= layer 0 =================
    uint4 xcur[8];
#pragma unroll
    for (int kt = 0; kt < 8; ++kt)
      xcur[kt] = *(const uint4*)(xp + ((((size_t)0 * 16 + m) * 8 + kt) * 64 + lane) * 8);

    for (int t = 0; t < 1024; ++t) {
      uint4 xnext[8];
      if (t < 1023) {
#pragma unroll
        for (int kt = 0; kt < 8; ++kt)
          xnext[kt] = *(const uint4*)(xp + ((((size_t)(t + 1) * 16 + m) * 8 + kt) * 64 + lane) * 8);
      }

      f32x4 acc[4];
#pragma unroll
      for (int g = 0; g < 4; ++g) acc[g] = (f32x4){0.f, 0.f, 0.f, 0.f};

      if (t > 0) {
        uint4 a[8];
#pragma unroll
        for (int kt = 0; kt < 8; ++kt)
          a[kt] = *(const uint4*)(&ha[(t - 1) & 1][swz(row, kt * 64 + hi * 16)]);
        // publish h1[t-1] in fragment layout (coalesced 1KB stores)
#pragma unroll
        for (int kt = 0; kt < 8; ++kt)
          *(uint4*)(h1p + ((((size_t)(t - 1) * 16 + m) * 8 + kt) * 64 + lane) * 8) = a[kt];
#pragma unroll
        for (int kt = 0; kt < 8; ++kt) {
          bf16x8 af = frag4(a[kt]);
#pragma unroll
          for (int g = 0; g < 4; ++g)
            acc[g] = __builtin_amdgcn_mfma_f32_16x16x32_bf16(af, bwhh[g][kt], acc[g], 0, 0, 0);
        }
      }
#pragma unroll
      for (int kt = 0; kt < 8; ++kt) {
        bf16x8 xf = frag4(xcur[kt]);
#pragma unroll
        for (int g = 0; g < 4; ++g)
          acc[g] = __builtin_amdgcn_mfma_f32_16x16x32_bf16(xf, bwih[g][kt], acc[g], 0, 0, 0);
      }

      // gates (lane-local) + LDS write of h1[t]
      unsigned myh[4];
#pragma unroll
      for (int q = 0; q < 4; ++q) {
        float ia = acc[0][q] + bias[0];
        float fa = acc[1][q] + bias[1];
        float ga = acc[2][q] + bias[2];
        float oa = acc[3][q] + bias[3];
        c[q] = sigm(fa) * c[q] + sigm(ia) * tanhfast(ga);
        myh[q] = (unsigned)f2bf(sigm(oa) * tanhfast(c[q]));
      }
#pragma unroll
      for (int q = 0; q < 4; ++q) {
        unsigned ov = (unsigned)__shfl_xor((int)myh[q], 1, 64);
        if (!(lane & 1)) {
          unsigned word = (myh[q] & 0xFFFFu) | (ov << 16);
          *(unsigned*)(&ha[t & 1][swz(r0 + q, u * 2)]) = word;
        }
      }
      __syncthreads();
      if (t < 1023) {
#pragma unroll
        for (int kt = 0; kt < 8; ++kt) xcur[kt] = xnext[kt];
      }
    }
    // epilogue: publish h1[1023] fragments
    {
#pragma unroll
      for (int kt = 0; kt < 8; ++kt) {
        uint4 a = *(const uint4*)(&ha[1][swz(row, kt * 64 + hi * 16)]);
        *(uint4*)(h1p + ((((size_t)1023 * 16 + m) * 8 + kt) * 64 + lane) * 8) = a;
      }
    }
  } else {
    // ================= layer 1 =================
    unsigned pc[32], pn[32];
    // prologue: load + spin h1p[0] fragments
    {
#pragma unroll
      for (int kt = 0; kt < 8; ++kt) {
        uint4 v = *(const uint4*)(h1p + ((((size_t)0 * 16 + m) * 8 + kt) * 64 + lane) * 8);
        pc[kt*4+0] = v.x; pc[kt*4+1] = v.y; pc[kt*4+2] = v.z; pc[kt*4+3] = v.w;
      }
      while (true) {
        unsigned bad = 0;
#pragma unroll
        for (int i = 0; i < 32; ++i) bad |= (pc[i] == SENT) ? 1u : 0u;
        if (!bad) break;
#pragma unroll
        for (int i = 0; i < 32; ++i)
          pc[i] = aload((const unsigned*)h1p +
                        ((((size_t)0 * 16 + m) * 8 + (i >> 2)) * 64 + lane) * 4 + (i & 3));
      }
    }

    for (int t = 0; t < 1024; ++t) {
      if (t < 1023) {
#pragma unroll
        for (int kt = 0; kt < 8; ++kt) {
          uint4 v = *(const uint4*)(h1p + ((((size_t)(t + 1) * 16 + m) * 8 + kt) * 64 + lane) * 8);
          pn[kt*4+0] = v.x; pn[kt*4+1] = v.y; pn[kt*4+2] = v.z; pn[kt*4+3] = v.w;
        }
      }

      f32x4 acc[4];
#pragma unroll
      for (int g = 0; g < 4; ++g) acc[g] = (f32x4){0.f, 0.f, 0.f, 0.f};

      if (t > 0) {
        uint4 a[8];
#pragma unroll
        for (int kt = 0; kt < 8; ++kt)
          a[kt] = *(const uint4*)(&ha[(t - 1) & 1][swz(row, kt * 64 + hi * 16)]);
#pragma unroll
        for (int kt = 0; kt < 8; ++kt) {
          bf16x8 af = frag4(a[kt]);
#pragma unroll
          for (int g = 0; g < 4; ++g)
            acc[g] = __builtin_amdgcn_mfma_f32_16x16x32_bf16(af, bwhh[g][kt], acc[g], 0, 0, 0);
        }
      }
#pragma unroll
      for (int kt = 0; kt < 8; ++kt) {
        bf16x8 pf = frag_of(pc[kt*4], pc[kt*4+1], pc[kt*4+2], pc[kt*4+3]);
#pragma unroll
        for (int g = 0; g < 4; ++g)
          acc[g] = __builtin_amdgcn_mfma_f32_16x16x32_bf16(pf, bwih[g][kt], acc[g], 0, 0, 0);
      }

      // gates + publish h2[t] (global, for fc) + LDS write
      unsigned myh[4];
#pragma unroll
      for (int q = 0; q < 4; ++q) {
        float ia = acc[0][q] + bias[0];
        float fa = acc[1][q] + bias[1];
        float ga = acc[2][q] + bias[2];
        float oa = acc[3][q] + bias[3];
        c[q] = sigm(fa) * c[q] + sigm(ia) * tanhfast(ga);
        myh[q] = (unsigned)f2bf(sigm(oa) * tanhfast(c[q]));
      }
#pragma unroll
      for (int q = 0; q < 4; ++q) {
        unsigned ov = (unsigned)__shfl_xor((int)myh[q], 1, 64);
        if (!(lane & 1)) {
          unsigned word = (myh[q] & 0xFFFFu) | (ov << 16);
          *(unsigned*)(&ha[t & 1][swz(r0 + q, u * 2)]) = word;
          *((unsigned*)h2 + (((size_t)t * 256 + 16 * m + r0 + q) * 256 + u) / 2) = word;
        }
      }

      // repair pass for the h1p[t+1] prefetch (rare; agent atomics bypass L1)
      if (t < 1023) {
        while (true) {
          unsigned bad = 0;
#pragma unroll
          for (int i = 0; i < 32; ++i) bad |= (pn[i] == SENT) ? 1u : 0u;
          if (!bad) break;
#pragma unroll
          for (int i = 0; i < 32; ++i)
            if (pn[i] == SENT)
              pn[i] = aload((const unsigned*)h1p +
                            ((((size_t)(t + 1) * 16 + m) * 8 + (i >> 2)) * 64 + lane) * 4 + (i & 3));
        }
      }
      __syncthreads();
      if (t < 1023) {
#pragma unroll
        for (int i = 0; i < 32; ++i) pc[i] = pn[i];
      }
    }
  }
}

// --------------------------------------------------------------------------
// logits = h2 @ fc_w^T + fc_b; out = logits - logsumexp(logits) (rows of 256).
// --------------------------------------------------------------------------
__global__ __launch_bounds__(256, 1) void fc_lsm(
    const unsigned short* __restrict__ h2,
    const unsigned short* __restrict__ Bp,
    const float* __restrict__ fcb,
    float* __restrict__ out)
{
  const int tid = threadIdx.x;
  const int wid = tid >> 6, lane = tid & 63;
  const int t = blockIdx.x >> 2, b0 = (blockIdx.x & 3) * 64;

  f32x4 acc[16];
#pragma unroll
  for (int nt = 0; nt < 16; ++nt) acc[nt] = (f32x4){0.f, 0.f, 0.f, 0.f};

#pragma unroll
  for (int kt = 0; kt < 8; ++kt) {
    bf16x8 a = *(const bf16x8*)(h2 +
        (((size_t)t * 256 + b0 + wid * 16 + (lane & 15)) * 256 +
         kt * 32 + (lane >> 4) * 8));
#pragma unroll
    for (int nt = 0; nt < 16; ++nt) {
      bf16x8 b = *(const bf16x8*)(Bp + (((size_t)nt * 8 + kt) * 64 + lane) * 8);
      acc[nt] = __builtin_amdgcn_mfma_f32_16x16x32_bf16(a, b, acc[nt], 0, 0, 0);
    }
  }
#pragma unroll
  for (int nt = 0; nt < 16; ++nt) {
    float bias = fcb[nt * 16 + (lane & 15)];
#pragma unroll
    for (int q = 0; q < 4; ++q) acc[nt][q] += bias;
  }

  float mx[4] = {-1e30f, -1e30f, -1e30f, -1e30f};
#pragma unroll
  for (int nt = 0; nt < 16; ++nt)
#pragma unroll
    for (int q = 0; q < 4; ++q) mx[q] = fmaxf(mx[q], acc[nt][q]);
#pragma unroll
  for (int d = 1; d < 16; d <<= 1)
#pragma unroll
    for (int q = 0; q < 4; ++q) mx[q] = fmaxf(mx[q], __shfl_xor(mx[q], d, 64));

  float sm[4] = {0.f, 0.f, 0.f, 0.f};
#pragma unroll
  for (int nt = 0; nt < 16; ++nt)
#pragma unroll
    for (int q = 0; q < 4; ++q) sm[q] += __expf(acc[nt][q] - mx[q]);
#pragma unroll
  for (int d = 1; d < 16; d <<= 1)
#pragma unroll
    for (int q = 0; q < 4; ++q) sm[q] += __shfl_xor(sm[q], d, 64);

  float lse[4];
#pragma unroll
  for (int q = 0; q < 4; ++q) lse[q] = mx[q] + __logf(sm[q]);

#pragma unroll
  for (int nt = 0; nt < 16; ++nt) {
#pragma unroll
    for (int q = 0; q < 4; ++q) {
      int b = b0 + wid * 16 + (lane >> 4) * 4 + q;
      out[((size_t)b * 1024 + t) * 256 + nt * 16 + (lane & 15)] = acc[nt][q] - lse[q];
    }
  }
}

// Unambiguous marker if workspace is too small.
__global__ void fill_marker(float* out, size_t nvals) {
  size_t i = (size_t)blockIdx.x * blockDim.x + threadIdx.x;
  if (i < nvals) out[i] = -7777.0f;
}

// --------------------------------------------------------------------------
extern "C" void kernel_launch(void* const* d_in, const int* in_sizes, int n_in,
                              void* d_out, int out_size, void* d_ws, size_t ws_size,
                              hipStream_t stream)
{
  (void)in_sizes; (void)n_in;
  const float* x    = (const float*)d_in[0];
  const float* wih0 = (const float*)d_in[1];
  const float* whh0 = (const float*)d_in[2];
  const float* bih0 = (const float*)d_in[3];
  const float* bhh0 = (const float*)d_in[4];
  const float* wih1 = (const float*)d_in[5];
  const float* whh1 = (const float*)d_in[6];
  const float* bih1 = (const float*)d_in[7];
  const float* bhh1 = (const float*)d_in[8];
  const float* fcw  = (const float*)d_in[9];
  const float* fcb  = (const float*)d_in[10];
  float* out = (float*)d_out;

  // workspace layout (bytes)
  const size_t o_wp0i = 0;
  const size_t o_wp0h = o_wp0i + 524288;
  const size_t o_wp1i = o_wp0h + 524288;
  const size_t o_wp1h = o_wp1i + 524288;
  const size_t o_fcp  = o_wp1h + 524288;        // 131072
  const size_t o_xp   = o_fcp  + 131072;        // 134217728
  const size_t o_h1p  = o_xp   + 134217728;     // 134217728
  const size_t o_h2   = o_h1p  + 134217728;     // 134217728
  const size_t need   = o_h2   + 134217728;     // ~405 MB

  if (ws_size < need) {
    size_t nv = (size_t)out_size;
    fill_marker<<<(unsigned)((nv + 1023) / 1024), 1024, 0, stream>>>(out, nv);
    return;
  }

  char* ws = (char*)d_ws;
  unsigned short* wp0i = (unsigned short*)(ws + o_wp0i);
  unsigned short* wp0h = (unsigned short*)(ws + o_wp0h);
  unsigned short* wp1i = (unsigned short*)(ws + o_wp1i);
  unsigned short* wp1h = (unsigned short*)(ws + o_wp1h);
  unsigned short* fcp  = (unsigned short*)(ws + o_fcp);
  unsigned short* xp   = (unsigned short*)(ws + o_xp);
  unsigned short* h1p  = (unsigned short*)(ws + o_h1p);
  unsigned short* h2   = (unsigned short*)(ws + o_h2);

  pack_w<<<512, 64, 0, stream>>>(wih0, wp0i);
  pack_w<<<512, 64, 0, stream>>>(whh0, wp0h);
  pack_w<<<512, 64, 0, stream>>>(wih1, wp1i);
  pack_w<<<512, 64, 0, stream>>>(whh1, wp1h);
  pack_w<<<128, 64, 0, stream>>>(fcw,  fcp);
  pack_x<<<1024, 64, 0, stream>>>(x, xp);

  // sentinel-init h1p (0xFF bytes -> 0xFFFFFFFF dwords)
  hipMemsetAsync(h1p, 0xFF, 134217728, stream);

  lstm_dual<<<32, 1024, 0, stream>>>(xp, wp0i, wp0h, bih0, bhh0,
                                     wp1i, wp1h, bih1, bhh1, h1p, h2);

  fc_lsm<<<4096, 256, 0, stream>>>(h2, fcp, fcb, out);
}

// Round 7
// 3439.699 us; speedup vs baseline: 9.0043x; 9.0043x over previous
//
#include <hip/hip_runtime.h>
#include <cstdint>
#include <cstddef>

// ---------------------------------------------------------------------------
// 2-layer LSTM (B=256, S=1024, V=H=256) + FC + log_softmax, MI355X/gfx950.
//
// Round 7: fragment-layout h exchange, fully wave-independent recurrence.
// 512 WGs x 64 thr (1 wave each): bid = w*32 + L*16 + m. Wave owns 16 units
// x 4 gates for 16 batch rows of m-group m, layer L; weights register-
// resident (256 VGPR; WG=64 => cap 512, the R6 spill fix).
// h stored in MFMA A-fragment layout [t][m][kt][lane]{16B}: producers do an
// in-wave LDS transpose (no barrier) + one coalesced 512B agent-store;
// consumers bulk-load the 8KB tile coalesced (16 x aload64), sentinel-spin
// (reload-all rounds), own chunk carried in regs (no same-addr RAW).
// L0 never waits on L1; fc reads h2 directly in frag layout.
//
// Phases: pack_w x5 -> pack_x -> memset h1f/h2f 0xFF -> lstm_dual -> fc_lsm.
// Workspace ~405 MB: packed weights | xp (134MB) | h1f (134MB) | h2f (134MB)
// ---------------------------------------------------------------------------

typedef __attribute__((ext_vector_type(8))) short bf16x8;
typedef __attribute__((ext_vector_type(4))) float f32x4;
typedef unsigned long long ull;

#define DEVFN __device__ __forceinline__

constexpr unsigned SENT = 0xFFFFFFFFu;   // bf16 NaN pair: unreachable for tanh outputs

DEVFN unsigned short f2bf(float f) {
  union { float f; unsigned u; } v; v.f = f;
  unsigned r = v.u + 0x7FFFu + ((v.u >> 16) & 1u);   // RNE
  return (unsigned short)(r >> 16);
}
DEVFN float sigm(float x) { return __builtin_amdgcn_rcpf(1.f + __expf(-x)); }
DEVFN float tanhfast(float x) {
  float ax = fabsf(x);
  float e  = __expf(-2.f * ax);
  float t  = (1.f - e) * __builtin_amdgcn_rcpf(1.f + e);
  return copysignf(t, x);
}
DEVFN ull aload64(const ull* p) {
  return __hip_atomic_load(p, __ATOMIC_RELAXED, __HIP_MEMORY_SCOPE_AGENT);
}
DEVFN void astore64(ull* p, ull v) {
  __hip_atomic_store(p, v, __ATOMIC_RELAXED, __HIP_MEMORY_SCOPE_AGENT);
}
DEVFN bool sent2(ull v) {
  return ((unsigned)v == SENT) || ((unsigned)(v >> 32) == SENT);
}
DEVFN bf16x8 fragu(ull a, ull b) {
  union { ull u[2]; bf16x8 f; } t; t.u[0] = a; t.u[1] = b; return t.f;
}
DEVFN bf16x8 frag4(uint4 u) { union { uint4 u; bf16x8 f; } t; t.u = u; return t.f; }

// --------------------------------------------------------------------------
// Pack W[col][k] (K=256) into B-fragment tiles:
//   dst[((nt*8+kt)*64+lane)*8 + j] = bf16( W[nt*16+(lane&15)][kt*32+(lane>>4)*8+j] )
// --------------------------------------------------------------------------
__global__ void pack_w(const float* __restrict__ w, unsigned short* __restrict__ dst) {
  int bid = blockIdx.x;           // nt*8 + kt
  int lane = threadIdx.x;
  int col = (bid >> 3) * 16 + (lane & 15);
  int k0  = (bid & 7) * 32 + (lane >> 4) * 8;
  const float* src = w + (size_t)col * 256 + k0;
  unsigned short* d = dst + ((size_t)bid * 64 + lane) * 8;
#pragma unroll
  for (int j = 0; j < 8; ++j) d[j] = f2bf(src[j]);
}

// --------------------------------------------------------------------------
// pack_x: x[b][t][v] f32 -> xp A-fragment layout bf16:
//   xp16B[((t*16+m)*8+kt)*64 + lane] = bf16( x[16m+(lane&15)][t][kt*32+(lane>>4)*8 + 0..7] )
// grid = 1024 blocks x 64 thr: bid = ((m*8+kt)*8 + tc), t in [tc*128, tc*128+128)
// --------------------------------------------------------------------------
__global__ void pack_x(const float* __restrict__ x, unsigned short* __restrict__ xp) {
  int bid = blockIdx.x, lane = threadIdx.x;
  int tc = bid & 7, kt = (bid >> 3) & 7, m = bid >> 6;
  int row = lane & 15, hi = lane >> 4;
  for (int t = tc * 128; t < tc * 128 + 128; ++t) {
    const float* s = x + ((size_t)(16 * m + row) * 1024 + t) * 256 + kt * 32 + hi * 8;
    float4 f0 = *(const float4*)s;
    float4 f1 = *(const float4*)(s + 4);
    uint4 o;
    o.x = f2bf(f0.x) | ((unsigned)f2bf(f0.y) << 16);
    o.y = f2bf(f0.z) | ((unsigned)f2bf(f0.w) << 16);
    o.z = f2bf(f1.x) | ((unsigned)f2bf(f1.y) << 16);
    o.w = f2bf(f1.z) | ((unsigned)f2bf(f1.w) << 16);
    *(uint4*)(xp + ((((size_t)t * 16 + m) * 8 + kt) * 64 + lane) * 8) = o;
  }
}

// --------------------------------------------------------------------------
// Dual-layer LSTM, independent waves. grid = 512 WGs x 64 thr.
// bid = w*32 + L*16 + m  (bid%8 == m%8: all 32 waves of an m-group, both
// layers, share an XCD under the %8 placement heuristic — perf only).
// Wave (L,m,w): units [16w,16w+16) x 4 gates, rows [16m,16m+16).
// Per step: issue ih loads -> issue h[t-1] frag loads -> ih-MFMA (overlaps
// flight) -> sentinel-spin h -> hh-MFMA -> gates -> in-wave transpose ->
// coalesced frag publish. Own chunk carried in regs across steps.
// --------------------------------------------------------------------------
__global__ __launch_bounds__(64, 1) void lstm_dual(
    const unsigned short* __restrict__ xp,
    const unsigned short* __restrict__ Wih0, const unsigned short* __restrict__ Whh0,
    const float* __restrict__ bih0, const float* __restrict__ bhh0,
    const unsigned short* __restrict__ Wih1, const unsigned short* __restrict__ Whh1,
    const float* __restrict__ bih1, const float* __restrict__ bhh1,
    unsigned short* __restrict__ h1f, unsigned short* __restrict__ h2f)
{
  __shared__ unsigned short tl[16][24];   // in-wave transpose tile (rows padded to 48B)
  const int lane = threadIdx.x;
  const int bid  = (int)blockIdx.x;
  const int m = bid & 15;
  const int L = (bid >> 4) & 1;
  const int w = bid >> 5;                 // unit-tile 0..15
  const int u = w * 16 + (lane & 15);
  const bool ownlane = (((lane >> 4) >> 1) == (w & 1));
  const int  mykt = w >> 1;               // frag kt this wave produces (half of it)

  const unsigned short* Wih = L ? Wih1 : Wih0;
  const unsigned short* Whh = L ? Whh1 : Whh0;
  const float* bihp = L ? bih1 : bih0;
  const float* bhhp = L ? bhh1 : bhh0;
  unsigned short* hown = L ? h2f : h1f;   // own-layer frag buffer (publish + hh)

  // register-resident weight B-fragments: nt = g*16 + w
  bf16x8 bwih[4][8], bwhh[4][8];
#pragma unroll
  for (int g = 0; g < 4; ++g)
#pragma unroll
    for (int kt = 0; kt < 8; ++kt) {
      bwih[g][kt] = *(const bf16x8*)(Wih + ((((size_t)(g * 16 + w)) * 8 + kt) * 64 + lane) * 8);
      bwhh[g][kt] = *(const bf16x8*)(Whh + ((((size_t)(g * 16 + w)) * 8 + kt) * 64 + lane) * 8);
    }

  float bias[4];
#pragma unroll
  for (int g = 0; g < 4; ++g) bias[g] = bihp[g * 256 + u] + bhhp[g * 256 + u];

  float c[4] = {0.f, 0.f, 0.f, 0.f};
  uint4 ownc = make_uint4(0, 0, 0, 0);    // own frag chunk of h[t-1] (t=0: unused)

  for (int t = 0; t < 1024; ++t) {
    const size_t tile  = ((size_t)t * 16 + m) * 8;        // frag tile index base
    const size_t ptile = ((size_t)(t - 1) * 16 + m) * 8;  // previous step

    // ---- 1) issue ih-source loads FIRST (so hh waits don't drain them) ----
    uint4 av[8];        // L0: x[t] frags (plain loads)
    ull  p1[8][2];      // L1: h1f[t] frags (atomic loads)
    if (!L) {
#pragma unroll
      for (int kt = 0; kt < 8; ++kt)
        av[kt] = *(const uint4*)(xp + ((tile + kt) * 64 + lane) * 8);
    } else {
      const ull* b1 = (const ull*)h1f;
#pragma unroll
      for (int kt = 0; kt < 8; ++kt) {
        p1[kt][0] = aload64(b1 + ((tile + kt) * 64 + lane) * 2);
        p1[kt][1] = aload64(b1 + ((tile + kt) * 64 + lane) * 2 + 1);
      }
    }

    // ---- 2) issue own-layer h[t-1] frag loads ----
    ull hv[8][2];
    const ull* bo = (const ull*)hown;
    if (t > 0) {
#pragma unroll
      for (int kt = 0; kt < 8; ++kt) {
        hv[kt][0] = aload64(bo + ((ptile + kt) * 64 + lane) * 2);
        hv[kt][1] = aload64(bo + ((ptile + kt) * 64 + lane) * 2 + 1);
      }
    }

    // ---- 3) ih-MFMA (L0: x ready; L1: validate h1f[t] first — L0 runs ahead) ----
    f32x4 acc[4];
#pragma unroll
    for (int g = 0; g < 4; ++g) acc[g] = (f32x4){0.f, 0.f, 0.f, 0.f};

    if (!L) {
#pragma unroll
      for (int kt = 0; kt < 8; ++kt) {
        bf16x8 a = frag4(av[kt]);
#pragma unroll
        for (int g = 0; g < 4; ++g)
          acc[g] = __builtin_amdgcn_mfma_f32_16x16x32_bf16(a, bwih[g][kt], acc[g], 0, 0, 0);
      }
    } else {
      int rounds = 0;
      while (true) {
        bool bad = false;
#pragma unroll
        for (int kt = 0; kt < 8; ++kt)
          bad = bad || sent2(p1[kt][0]) || sent2(p1[kt][1]);
        if (!__any(bad)) break;
        if (++rounds > 4) __builtin_amdgcn_s_sleep(1);
        const ull* b1 = (const ull*)h1f;
#pragma unroll
        for (int kt = 0; kt < 8; ++kt) {
          p1[kt][0] = aload64(b1 + ((tile + kt) * 64 + lane) * 2);
          p1[kt][1] = aload64(b1 + ((tile + kt) * 64 + lane) * 2 + 1);
        }
      }
#pragma unroll
      for (int kt = 0; kt < 8; ++kt) {
        bf16x8 a = fragu(p1[kt][0], p1[kt][1]);
#pragma unroll
        for (int g = 0; g < 4; ++g)
          acc[g] = __builtin_amdgcn_mfma_f32_16x16x32_bf16(a, bwih[g][kt], acc[g], 0, 0, 0);
      }
    }

    // ---- 4) sentinel-spin own-layer h[t-1], then hh-MFMA ----
    if (t > 0) {
      int rounds = 0;
      while (true) {
        // own chunk: overwrite from regs (never trust racy own-addr loads)
#pragma unroll
        for (int kt = 0; kt < 8; ++kt)
          if (kt == mykt && ownlane) {
            hv[kt][0] = ((ull)ownc.y << 32) | ownc.x;
            hv[kt][1] = ((ull)ownc.w << 32) | ownc.z;
          }
        bool bad = false;
#pragma unroll
        for (int kt = 0; kt < 8; ++kt)
          bad = bad || sent2(hv[kt][0]) || sent2(hv[kt][1]);
        if (!__any(bad)) break;
        if (++rounds > 4) __builtin_amdgcn_s_sleep(1);
#pragma unroll
        for (int kt = 0; kt < 8; ++kt) {
          hv[kt][0] = aload64(bo + ((ptile + kt) * 64 + lane) * 2);
          hv[kt][1] = aload64(bo + ((ptile + kt) * 64 + lane) * 2 + 1);
        }
      }
#pragma unroll
      for (int kt = 0; kt < 8; ++kt) {
        bf16x8 a = fragu(hv[kt][0], hv[kt][1]);
#pragma unroll
        for (int g = 0; g < 4; ++g)
          acc[g] = __builtin_amdgcn_mfma_f32_16x16x32_bf16(a, bwhh[g][kt], acc[g], 0, 0, 0);
      }
    }

    // ---- 5) gates (lane-local, C layout: row 4*(lane>>4)+q, unit u) ----
    float hq[4];
#pragma unroll
    for (int q = 0; q < 4; ++q) {
      float ia = acc[0][q] + bias[0];
      float fa = acc[1][q] + bias[1];
      float ga = acc[2][q] + bias[2];
      float oa = acc[3][q] + bias[3];
      c[q] = sigm(fa) * c[q] + sigm(ia) * tanhfast(ga);
      hq[q] = sigm(oa) * tanhfast(c[q]);
    }

    // ---- 6) in-wave transpose C-layout -> A-frag layout (no barrier) ----
#pragma unroll
    for (int q = 0; q < 4; ++q)
      tl[(lane >> 4) * 4 + q][lane & 15] = f2bf(hq[q]);
    // single wave: compiler inserts lgkmcnt before the dependent read
    uint4 nown = *(const uint4*)(&tl[lane & 15][((lane >> 4) & 1) * 8]);
    ownc = nown;

    // ---- 7) publish own frag chunk (coalesced 512B, 32 active lanes) ----
    if (ownlane) {
      ull* d = (ull*)hown + ((tile + mykt) * 64 + lane) * 2;
      astore64(d,     ((ull)nown.y << 32) | nown.x);
      astore64(d + 1, ((ull)nown.w << 32) | nown.z);
    }
  }
}

// --------------------------------------------------------------------------
// logits = h2 @ fc_w^T + fc_b; out = logits - logsumexp (rows of 256).
// h2 consumed directly in fragment layout. Block = 256 thr (4 waves);
// tile = 64 rows (fixed t) x 256 cols. grid = 4096 (t = bid>>2).
// --------------------------------------------------------------------------
__global__ __launch_bounds__(256, 1) void fc_lsm(
    const unsigned short* __restrict__ h2f,
    const unsigned short* __restrict__ Bp,
    const float* __restrict__ fcb,
    float* __restrict__ out)
{
  const int tid = threadIdx.x;
  const int wid = tid >> 6, lane = tid & 63;
  const int t = blockIdx.x >> 2;
  const int mloc = (blockIdx.x & 3) * 4 + wid;   // m-group handled by this wave

  f32x4 acc[16];
#pragma unroll
  for (int nt = 0; nt < 16; ++nt) acc[nt] = (f32x4){0.f, 0.f, 0.f, 0.f};

#pragma unroll
  for (int kt = 0; kt < 8; ++kt) {
    bf16x8 a = *(const bf16x8*)(h2f + ((((size_t)t * 16 + mloc) * 8 + kt) * 64 + lane) * 8);
#pragma unroll
    for (int nt = 0; nt < 16; ++nt) {
      bf16x8 b = *(const bf16x8*)(Bp + (((size_t)nt * 8 + kt) * 64 + lane) * 8);
      acc[nt] = __builtin_amdgcn_mfma_f32_16x16x32_bf16(a, b, acc[nt], 0, 0, 0);
    }
  }
#pragma unroll
  for (int nt = 0; nt < 16; ++nt) {
    float bias = fcb[nt * 16 + (lane & 15)];
#pragma unroll
    for (int q = 0; q < 4; ++q) acc[nt][q] += bias;
  }

  float mx[4] = {-1e30f, -1e30f, -1e30f, -1e30f};
#pragma unroll
  for (int nt = 0; nt < 16; ++nt)
#pragma unroll
    for (int q = 0; q < 4; ++q) mx[q] = fmaxf(mx[q], acc[nt][q]);
#pragma unroll
  for (int d = 1; d < 16; d <<= 1)
#pragma unroll
    for (int q = 0; q < 4; ++q) mx[q] = fmaxf(mx[q], __shfl_xor(mx[q], d, 64));

  float sm[4] = {0.f, 0.f, 0.f, 0.f};
#pragma unroll
  for (int nt = 0; nt < 16; ++nt)
#pragma unroll
    for (int q = 0; q < 4; ++q) sm[q] += __expf(acc[nt][q] - mx[q]);
#pragma unroll
  for (int d = 1; d < 16; d <<= 1)
#pragma unroll
    for (int q = 0; q < 4; ++q) sm[q] += __shfl_xor(sm[q], d, 64);

  float lse[4];
#pragma unroll
  for (int q = 0; q < 4; ++q) lse[q] = mx[q] + __logf(sm[q]);

#pragma unroll
  for (int nt = 0; nt < 16; ++nt) {
#pragma unroll
    for (int q = 0; q < 4; ++q) {
      int b = mloc * 16 + (lane >> 4) * 4 + q;
      out[((size_t)b * 1024 + t) * 256 + nt * 16 + (lane & 15)] = acc[nt][q] - lse[q];
    }
  }
}

// Unambiguous marker if workspace is too small.
__global__ void fill_marker(float* out, size_t nvals) {
  size_t i = (size_t)blockIdx.x * blockDim.x + threadIdx.x;
  if (i < nvals) out[i] = -7777.0f;
}

// --------------------------------------------------------------------------
extern "C" void kernel_launch(void* const* d_in, const int* in_sizes, int n_in,
                              void* d_out, int out_size, void* d_ws, size_t ws_size,
                              hipStream_t stream)
{
  (void)in_sizes; (void)n_in;
  const float* x    = (const float*)d_in[0];
  const float* wih0 = (const float*)d_in[1];
  const float* whh0 = (const float*)d_in[2];
  const float* bih0 = (const float*)d_in[3];
  const float* bhh0 = (const float*)d_in[4];
  const float* wih1 = (const float*)d_in[5];
  const float* whh1 = (const float*)d_in[6];
  const float* bih1 = (const float*)d_in[7];
  const float* bhh1 = (const float*)d_in[8];
  const float* fcw  = (const float*)d_in[9];
  const float* fcb  = (const float*)d_in[10];
  float* out = (float*)d_out;

  // workspace layout (bytes)
  const size_t o_wp0i = 0;
  const size_t o_wp0h = o_wp0i + 524288;
  const size_t o_wp1i = o_wp0h + 524288;
  const size_t o_wp1h = o_wp1i + 524288;
  const size_t o_fcp  = o_wp1h + 524288;        // 131072
  const size_t o_xp   = o_fcp  + 131072;        // 134217728
  const size_t o_h1f  = o_xp   + 134217728;     // 134217728
  const size_t o_h2f  = o_h1f  + 134217728;     // 134217728
  const size_t need   = o_h2f  + 134217728;     // ~405 MB

  if (ws_size < need) {
    size_t nv = (size_t)out_size;
    fill_marker<<<(unsigned)((nv + 1023) / 1024), 1024, 0, stream>>>(out, nv);
    return;
  }

  char* ws = (char*)d_ws;
  unsigned short* wp0i = (unsigned short*)(ws + o_wp0i);
  unsigned short* wp0h = (unsigned short*)(ws + o_wp0h);
  unsigned short* wp1i = (unsigned short*)(ws + o_wp1i);
  unsigned short* wp1h = (unsigned short*)(ws + o_wp1h);
  unsigned short* fcp  = (unsigned short*)(ws + o_fcp);
  unsigned short* xp   = (unsigned short*)(ws + o_xp);
  unsigned short* h1f  = (unsigned short*)(ws + o_h1f);
  unsigned short* h2f  = (unsigned short*)(ws + o_h2f);

  pack_w<<<512, 64, 0, stream>>>(wih0, wp0i);
  pack_w<<<512, 64, 0, stream>>>(whh0, wp0h);
  pack_w<<<512, 64, 0, stream>>>(wih1, wp1i);
  pack_w<<<512, 64, 0, stream>>>(whh1, wp1h);
  pack_w<<<128, 64, 0, stream>>>(fcw,  fcp);
  pack_x<<<1024, 64, 0, stream>>>(x, xp);

  // sentinel-init frag buffers (0xFF bytes -> 0xFFFFFFFF dwords)
  hipMemsetAsync(h1f, 0xFF, 134217728, stream);
  hipMemsetAsync(h2f, 0xFF, 134217728, stream);

  lstm_dual<<<512, 64, 0, stream>>>(xp, wp0i, wp0h, bih0, bhh0,
                                    wp1i, wp1h, bih1, bhh1, h1f, h2f);

  fc_lsm<<<4096, 256, 0, stream>>>(h2f, fcp, fcb, out);
}